// Round 4
// baseline (58.496 us; speedup 1.0000x reference)
//
#include <hip/hip_runtime.h>
#include <math.h>

// Problem constants (fixed by the reference setup)
constexpr int N = 4096;
constexpr int E = 128;
constexpr int H = 8;
constexpr int D = 16;      // E / H
constexpr int SPAN = 50;

// ---------------------------------------------------------------------------
// Kernel 1: fused projections  q = X@Wq+bq, k, v, and b = attn_bias@Wfe+bfe
// Grid 256 x 512 threads; 16-row tile. X tiles stored TRANSPOSED in LDS
// (xt[mat][k][17]) so the k-loop is: 3 coalesced float4 W loads (global,
// L2-resident) + 3 broadcast ds_read_b32 + 12 FMA per iteration.
// Thread = (c4 = tid&31 -> 4 output cols, rh = tid>>5 -> 1 row).
// ---------------------------------------------------------------------------
__global__ __launch_bounds__(512) void proj_kernel(
    const float* __restrict__ query, const float* __restrict__ key,
    const float* __restrict__ value, const float* __restrict__ attn_bias,
    const float* __restrict__ Wq, const float* __restrict__ bq,
    const float* __restrict__ Wk, const float* __restrict__ bk,
    const float* __restrict__ Wv, const float* __restrict__ bv,
    const float* __restrict__ Wfe, const float* __restrict__ bfe,
    float* __restrict__ qo, float* __restrict__ ko,
    float* __restrict__ vo, float* __restrict__ bo_)
{
    __shared__ float xt[3][E][17];   // transposed X tiles, pad 17
    __shared__ float ab[16][8];

    const int tid  = threadIdx.x;
    const int c4   = tid & 31;       // float4 column group
    const int rh   = tid >> 5;       // row within tile (0..15)
    const int row0 = blockIdx.x * 16;

    // ---- load + transpose the three X tiles ----
    {
        const int r  = tid >> 5;     // 0..15
        const int cq = tid & 31;     // float4 quad
        float4 t;
        t = ((const float4*)(query + (size_t)(row0 + r) * E))[cq];
        xt[0][cq * 4 + 0][r] = t.x; xt[0][cq * 4 + 1][r] = t.y;
        xt[0][cq * 4 + 2][r] = t.z; xt[0][cq * 4 + 3][r] = t.w;
        t = ((const float4*)(key + (size_t)(row0 + r) * E))[cq];
        xt[1][cq * 4 + 0][r] = t.x; xt[1][cq * 4 + 1][r] = t.y;
        xt[1][cq * 4 + 2][r] = t.z; xt[1][cq * 4 + 3][r] = t.w;
        t = ((const float4*)(value + (size_t)(row0 + r) * E))[cq];
        xt[2][cq * 4 + 0][r] = t.x; xt[2][cq * 4 + 1][r] = t.y;
        xt[2][cq * 4 + 2][r] = t.z; xt[2][cq * 4 + 3][r] = t.w;
    }
    if (tid < 128) ab[tid >> 3][tid & 7] = attn_bias[(size_t)row0 * H + tid];
    __syncthreads();

    float4 aq = ((const float4*)bq)[c4];
    float4 ak = ((const float4*)bk)[c4];
    float4 av = ((const float4*)bv)[c4];
    float4 ai = ((const float4*)bfe)[c4];

    const float4* wqp = (const float4*)Wq + c4;
    const float4* wkp = (const float4*)Wk + c4;
    const float4* wvp = (const float4*)Wv + c4;

    #pragma unroll 4
    for (int kk = 0; kk < E; ++kk) {
        const float4 wq = wqp[kk * 32];
        const float4 wk = wkp[kk * 32];
        const float4 wv = wvp[kk * 32];
        const float xq = xt[0][kk][rh];
        const float xk = xt[1][kk][rh];
        const float xv = xt[2][kk][rh];
        aq.x = fmaf(xq, wq.x, aq.x); aq.y = fmaf(xq, wq.y, aq.y);
        aq.z = fmaf(xq, wq.z, aq.z); aq.w = fmaf(xq, wq.w, aq.w);
        ak.x = fmaf(xk, wk.x, ak.x); ak.y = fmaf(xk, wk.y, ak.y);
        ak.z = fmaf(xk, wk.z, ak.z); ak.w = fmaf(xk, wk.w, ak.w);
        av.x = fmaf(xv, wv.x, av.x); av.y = fmaf(xv, wv.y, av.y);
        av.z = fmaf(xv, wv.z, av.z); av.w = fmaf(xv, wv.w, av.w);
    }

    #pragma unroll
    for (int hh = 0; hh < H; ++hh) {
        const float4 wf = ((const float4*)(Wfe + (size_t)hh * E))[c4];
        const float a = ab[rh][hh];
        ai.x = fmaf(a, wf.x, ai.x); ai.y = fmaf(a, wf.y, ai.y);
        ai.z = fmaf(a, wf.z, ai.z); ai.w = fmaf(a, wf.w, ai.w);
    }

    const size_t ro = (size_t)(row0 + rh) * E;
    ((float4*)(qo  + ro))[c4] = aq;
    ((float4*)(ko  + ro))[c4] = ak;
    ((float4*)(vo  + ro))[c4] = av;
    ((float4*)(bo_ + ro))[c4] = ai;
}

// ---------------------------------------------------------------------------
// Kernel 2: banded attention. One wave (64-thread block) per (8-row tile,
// head); 4096 blocks; ZERO barriers, zero cross-wave state.
// Phase 1: all 8 rows' scores -> exp -> LDS (8 independent dep chains).
// Phase 2: all 8 PV reductions (ds_read_b128 V, branchless w-loop over the
// zero-padded ew rows), 4-step shfl reduce, prob-sum folded in.
// ---------------------------------------------------------------------------
__global__ __launch_bounds__(64) void attn_kernel(
    const float* __restrict__ q, const float* __restrict__ k,
    const float* __restrict__ v, const float* __restrict__ b,
    float* __restrict__ attn)
{
    __shared__ __align__(16) float4 vt4[128 * 4];  // V rows [base, base+128)
    __shared__ float ew[8 * 112];                  // exp weights, pad-zeroed

    const int lane = threadIdx.x;
    const int bid  = blockIdx.x;
    const int h    = bid & 7;
    const int i0   = (bid >> 3) * 8;
    const int base = i0 - SPAN;

    // zero the pad region ew[r][101..111]
    for (int z = lane; z < 88; z += 64) {
        const int r = z / 11;
        ew[r * 112 + 101 + (z - r * 11)] = 0.f;
    }

    // ---- stage V rows into LDS (contiguous, b128 granularity) ----
    {
        const int x  = lane & 3;
        const int rr = lane >> 2;
        #pragma unroll
        for (int rep = 0; rep < 8; ++rep) {
            const int r = rep * 16 + rr;
            int j = base + r;
            j = j < 0 ? 0 : (j > N - 1 ? N - 1 : j);
            vt4[r * 4 + x] = ((const float4*)(v + (size_t)j * E + h * D))[x];
        }
    }

    // ---- K/B(feature) rows for this lane's two positions -> registers ----
    const int p0 = base + lane;
    const int p1 = p0 + 64;
    const bool in0 = (p0 >= 0) && (p0 < N);
    const bool in1 = (p1 < N);
    const int c0 = p0 < 0 ? 0 : (p0 > N - 1 ? N - 1 : p0);
    const int c1 = p1 > N - 1 ? N - 1 : p1;

    float k0[16], k1[16], g0[16], g1[16];
    {
        const float4* kp0 = (const float4*)(k + (size_t)c0 * E + h * D);
        const float4* kp1 = (const float4*)(k + (size_t)c1 * E + h * D);
        const float4* gp0 = (const float4*)(b + (size_t)c0 * E + h * D);
        const float4* gp1 = (const float4*)(b + (size_t)c1 * E + h * D);
        #pragma unroll
        for (int x = 0; x < 4; ++x) {
            float4 t;
            t = kp0[x]; k0[4*x]=t.x; k0[4*x+1]=t.y; k0[4*x+2]=t.z; k0[4*x+3]=t.w;
            t = kp1[x]; k1[4*x]=t.x; k1[4*x+1]=t.y; k1[4*x+2]=t.z; k1[4*x+3]=t.w;
            t = gp0[x]; g0[4*x]=t.x; g0[4*x+1]=t.y; g0[4*x+2]=t.z; g0[4*x+3]=t.w;
            t = gp1[x]; g1[4*x]=t.x; g1[4*x+1]=t.y; g1[4*x+2]=t.z; g1[4*x+3]=t.w;
        }
    }

    const float scale = 1.0f / 64.0f;   // 1/sqrt(4096)

    // ---- phase 1: scores + exp for all 8 rows ----
    #pragma unroll 4
    for (int r = 0; r < 8; ++r) {
        const float* qp = q + (size_t)(i0 + r) * E + h * D;  // wave-uniform
        const float* bp = b + (size_t)(i0 + r) * E + h * D;

        float sq0 = 0.f, sq1 = 0.f, sb0 = 0.f, sb1 = 0.f;
        #pragma unroll
        for (int x = 0; x < 16; ++x) {
            const float qv = qp[x];
            const float bv = bp[x];
            sq0 = fmaf(qv, k0[x], sq0);
            sq1 = fmaf(qv, k1[x], sq1);
            sb0 = fmaf(bv, g0[x], sb0);
            sb1 = fmaf(bv, g1[x], sb1);
        }
        const bool ok0 = in0 && (lane >= r);
        const bool ok1 = in1 && (lane <= r + 36);
        const float s0 = ok0 ? sq0 * scale + sb0 : -INFINITY;
        const float s1 = ok1 ? sq1 * scale + sb1 : -INFINITY;

        // no max-subtraction: scores are O(10), exp safe in fp32,
        // softmax without the shift is mathematically identical.
        const float e0 = __expf(s0);   // -inf -> 0
        const float e1 = __expf(s1);

        if (lane >= r)      ew[r * 112 + (lane - r)]      = e0;
        if (lane <= r + 36) ew[r * 112 + (64 + lane - r)] = e1;
    }

    // ---- phase 2: PV for all 8 rows (single wave: ds ordering is implicit)
    const int dq = lane & 3;     // float4 quad of head dim
    const int g  = lane >> 2;    // window group (16)

    #pragma unroll 2
    for (int r = 0; r < 8; ++r) {
        float ax = 0.f, ay = 0.f, az = 0.f, aw = 0.f, as = 0.f;
        #pragma unroll
        for (int it = 0; it < 7; ++it) {
            const int w = it * 16 + g;              // <= 111, pad is zero
            const float p = ew[r * 112 + w];
            const float4 vv = vt4[(w + r) * 4 + dq];
            ax = fmaf(p, vv.x, ax); ay = fmaf(p, vv.y, ay);
            az = fmaf(p, vv.z, az); aw = fmaf(p, vv.w, aw);
            as += p;
        }
        #pragma unroll
        for (int off = 4; off <= 32; off <<= 1) {
            ax += __shfl_xor(ax, off);
            ay += __shfl_xor(ay, off);
            az += __shfl_xor(az, off);
            aw += __shfl_xor(aw, off);
            as += __shfl_xor(as, off);
        }
        if (g == 0) {
            const float inv = 1.0f / as;
            ((float4*)(attn + (size_t)(i0 + r) * E + h * D))[dq] =
                make_float4(ax * inv, ay * inv, az * inv, aw * inv);
        }
    }
}

// ---------------------------------------------------------------------------
// Kernel 3: output projection  out = attn @ Wo + bo  (R2 version, verbatim)
// ---------------------------------------------------------------------------
__global__ __launch_bounds__(256) void out_kernel(
    const float* __restrict__ attn, const float* __restrict__ Wo,
    const float* __restrict__ bo, float* __restrict__ out)
{
    __shared__ float xa[8][E];

    const int tid  = threadIdx.x;
    const int col  = tid & 127;
    const int half = tid >> 7;
    const int row0 = blockIdx.x * 8;

    #pragma unroll
    for (int m = 0; m < 4; ++m) {
        const int e = tid + 256 * m;
        const int r = e >> 7, c = e & 127;
        xa[r][c] = attn[(size_t)(row0 + r) * E + c];
    }
    __syncthreads();

    const int r0 = half * 4;
    float acc[4];
    {
        const float t = bo[col];
        #pragma unroll
        for (int r = 0; r < 4; ++r) acc[r] = t;
    }

    for (int kk = 0; kk < E; kk += 4) {
        float w[4];
        #pragma unroll
        for (int u = 0; u < 4; ++u)
            w[u] = Wo[(size_t)(kk + u) * E + col];
        #pragma unroll
        for (int r = 0; r < 4; ++r) {
            const float4 x = *(const float4*)&xa[r0 + r][kk];
            acc[r] = fmaf(x.x, w[0], acc[r]); acc[r] = fmaf(x.y, w[1], acc[r]);
            acc[r] = fmaf(x.z, w[2], acc[r]); acc[r] = fmaf(x.w, w[3], acc[r]);
        }
    }

    #pragma unroll
    for (int r = 0; r < 4; ++r)
        out[(size_t)(row0 + r0 + r) * E + col] = acc[r];
}

// ---------------------------------------------------------------------------
extern "C" void kernel_launch(void* const* d_in, const int* in_sizes, int n_in,
                              void* d_out, int out_size, void* d_ws, size_t ws_size,
                              hipStream_t stream) {
    const float* query     = (const float*)d_in[0];
    const float* key       = (const float*)d_in[1];
    const float* value     = (const float*)d_in[2];
    const float* attn_bias = (const float*)d_in[3];
    const float* Wq  = (const float*)d_in[4];
    const float* bq  = (const float*)d_in[5];
    const float* Wk  = (const float*)d_in[6];
    const float* bk  = (const float*)d_in[7];
    const float* Wv  = (const float*)d_in[8];
    const float* bv  = (const float*)d_in[9];
    const float* Wo  = (const float*)d_in[10];
    const float* bo  = (const float*)d_in[11];
    const float* Wfe = (const float*)d_in[12];
    const float* bfe = (const float*)d_in[13];

    float* ws = (float*)d_ws;
    const int NE = N * E;
    float* qw    = ws;
    float* kw    = ws + 1 * NE;
    float* vw    = ws + 2 * NE;
    float* bw    = ws + 3 * NE;
    float* attnw = ws + 4 * NE;

    proj_kernel<<<N / 16, 512, 0, stream>>>(query, key, value, attn_bias,
                                            Wq, bq, Wk, bk, Wv, bv, Wfe, bfe,
                                            qw, kw, vw, bw);
    attn_kernel<<<(N / 8) * H, 64, 0, stream>>>(qw, kw, vw, bw, attnw);
    out_kernel<<<N / 8, 256, 0, stream>>>(attnw, Wo, bo, (float*)d_out);
}

// Round 5
// 51.459 us; speedup vs baseline: 1.1367x; 1.1367x over previous
//
#include <hip/hip_runtime.h>
#include <math.h>

// Problem constants (fixed by the reference setup)
constexpr int N = 4096;
constexpr int E = 128;
constexpr int H = 8;
constexpr int D = 16;      // E / H
constexpr int SPAN = 50;

// ---------------------------------------------------------------------------
// Shared GEMM building blocks.
// Block = 128 threads (2 waves). Tile = 8 rows x 128 cols. Split-K: wave h
// (h = tid>>6) handles k in [h*64, h*64+64). Thread computes a 4x4 register
// block: rows r0..r0+3 (r0 = ((tid>>5)&1)*4), cols c4*4..c4*4+3 (c4 = tid&31).
// Inner step (4 k's): 4 ds_read_b128 (X rows, 2-way broadcast -> free) +
// 4 coalesced global float4 W loads + 64 FMA.
// Halves are combined through an LDS partial buffer part[2][8][132].
// ---------------------------------------------------------------------------
__device__ __forceinline__ void gemm_fma4(const float4 x, const float4 w0,
                                          const float4 w1, const float4 w2,
                                          const float4 w3, float4& a)
{
    a.x = fmaf(x.x, w0.x, a.x); a.y = fmaf(x.x, w0.y, a.y);
    a.z = fmaf(x.x, w0.z, a.z); a.w = fmaf(x.x, w0.w, a.w);
    a.x = fmaf(x.y, w1.x, a.x); a.y = fmaf(x.y, w1.y, a.y);
    a.z = fmaf(x.y, w1.z, a.z); a.w = fmaf(x.y, w1.w, a.w);
    a.x = fmaf(x.z, w2.x, a.x); a.y = fmaf(x.z, w2.y, a.y);
    a.z = fmaf(x.z, w2.z, a.z); a.w = fmaf(x.z, w2.w, a.w);
    a.x = fmaf(x.w, w3.x, a.x); a.y = fmaf(x.w, w3.y, a.y);
    a.z = fmaf(x.w, w3.z, a.z); a.w = fmaf(x.w, w3.w, a.w);
}

__device__ __forceinline__ void gemm_half_8x128(
    const float* __restrict__ xs,    // staged [8][128] tile rows
    const float* __restrict__ Wm,    // weight [128][128]
    int h, int c4, int r0, float4 acc[4])
{
    const int kbase = h * 64;
    #pragma unroll 2
    for (int kk = 0; kk < 64; kk += 4) {
        const int k = kbase + kk;
        const float4 w0 = ((const float4*)(Wm + (size_t)(k + 0) * E))[c4];
        const float4 w1 = ((const float4*)(Wm + (size_t)(k + 1) * E))[c4];
        const float4 w2 = ((const float4*)(Wm + (size_t)(k + 2) * E))[c4];
        const float4 w3 = ((const float4*)(Wm + (size_t)(k + 3) * E))[c4];
        #pragma unroll
        for (int i = 0; i < 4; ++i) {
            const float4 x = *(const float4*)&xs[(r0 + i) * E + k];
            gemm_fma4(x, w0, w1, w2, w3, acc[i]);
        }
    }
}

__device__ __forceinline__ void combine_store(
    float* __restrict__ part,        // [2][8][132] floats
    const float4 acc[4], int h, int c4, int r0, int tid,
    const float* __restrict__ bias, float* __restrict__ outp, int row0)
{
    #pragma unroll
    for (int i = 0; i < 4; ++i)
        *(float4*)&part[(size_t)(h * 8 + r0 + i) * 132 + c4 * 4] = acc[i];
    __syncthreads();
    #pragma unroll
    for (int rr = 0; rr < 2; ++rr) {
        const int idx = tid + 128 * rr;          // 0..255 -> 256 float4s
        const int row = idx >> 5, q = idx & 31;
        const float4 p0 = *(const float4*)&part[(size_t)row * 132 + q * 4];
        const float4 p1 = *(const float4*)&part[(size_t)(8 + row) * 132 + q * 4];
        const float4 bb = ((const float4*)bias)[q];
        const float4 o  = make_float4(p0.x + p1.x + bb.x, p0.y + p1.y + bb.y,
                                      p0.z + p1.z + bb.z, p0.w + p1.w + bb.w);
        *(float4*)&outp[(size_t)(row0 + row) * E + q * 4] = o;
    }
    __syncthreads();   // part is reused by the next matrix
}

// ---------------------------------------------------------------------------
// Kernel 1: fused projections  q = X@Wq+bq, k, v, and b = attn_bias@Wfe+bfe
// ---------------------------------------------------------------------------
__global__ __launch_bounds__(128) void proj_kernel(
    const float* __restrict__ query, const float* __restrict__ key,
    const float* __restrict__ value, const float* __restrict__ attn_bias,
    const float* __restrict__ Wq, const float* __restrict__ bq,
    const float* __restrict__ Wk, const float* __restrict__ bk,
    const float* __restrict__ Wv, const float* __restrict__ bv,
    const float* __restrict__ Wfe, const float* __restrict__ bfe,
    float* __restrict__ qo, float* __restrict__ ko,
    float* __restrict__ vo, float* __restrict__ bo_)
{
    __shared__ float xs[3][8][E];
    __shared__ float ab[8][8];
    __shared__ float part[2 * 8 * 132];

    const int tid  = threadIdx.x;
    const int c4   = tid & 31;
    const int r0   = ((tid >> 5) & 1) * 4;
    const int h    = tid >> 6;
    const int row0 = blockIdx.x * 8;

    // ---- stage the three 8x128 X tiles (coalesced float4) + attn_bias ----
    #pragma unroll
    for (int m = 0; m < 3; ++m) {
        const float* s = (m == 0) ? query : (m == 1) ? key : value;
        #pragma unroll
        for (int rr = 0; rr < 2; ++rr) {
            const int idx = tid + 128 * rr;
            const int row = idx >> 5, q = idx & 31;
            *(float4*)&xs[m][row][q * 4] =
                ((const float4*)(s + (size_t)(row0 + row) * E))[q];
        }
    }
    if (tid < 64) ab[tid >> 3][tid & 7] = attn_bias[(size_t)row0 * H + tid];
    __syncthreads();

    float4 acc[4];

    // ---- q projection ----
    #pragma unroll
    for (int i = 0; i < 4; ++i) acc[i] = make_float4(0.f, 0.f, 0.f, 0.f);
    gemm_half_8x128(&xs[0][0][0], Wq, h, c4, r0, acc);
    combine_store(part, acc, h, c4, r0, tid, bq, qo, row0);

    // ---- k projection ----
    #pragma unroll
    for (int i = 0; i < 4; ++i) acc[i] = make_float4(0.f, 0.f, 0.f, 0.f);
    gemm_half_8x128(&xs[1][0][0], Wk, h, c4, r0, acc);
    combine_store(part, acc, h, c4, r0, tid, bk, ko, row0);

    // ---- v projection ----
    #pragma unroll
    for (int i = 0; i < 4; ++i) acc[i] = make_float4(0.f, 0.f, 0.f, 0.f);
    gemm_half_8x128(&xs[2][0][0], Wv, h, c4, r0, acc);
    combine_store(part, acc, h, c4, r0, tid, bv, vo, row0);

    // ---- feature projection (K = 8, split 4/4 across waves) ----
    #pragma unroll
    for (int i = 0; i < 4; ++i) acc[i] = make_float4(0.f, 0.f, 0.f, 0.f);
    {
        const float4 w0 = ((const float4*)(Wfe + (size_t)(h * 4 + 0) * E))[c4];
        const float4 w1 = ((const float4*)(Wfe + (size_t)(h * 4 + 1) * E))[c4];
        const float4 w2 = ((const float4*)(Wfe + (size_t)(h * 4 + 2) * E))[c4];
        const float4 w3 = ((const float4*)(Wfe + (size_t)(h * 4 + 3) * E))[c4];
        #pragma unroll
        for (int i = 0; i < 4; ++i) {
            const float4 x = *(const float4*)&ab[r0 + i][h * 4];
            gemm_fma4(x, w0, w1, w2, w3, acc[i]);
        }
    }
    combine_store(part, acc, h, c4, r0, tid, bfe, bo_, row0);
}

// ---------------------------------------------------------------------------
// Kernel 2: banded attention (R2 version, verbatim — known good).
// One 64-thread block per (8-row tile, head).
// ---------------------------------------------------------------------------
__global__ __launch_bounds__(64, 4) void attn_kernel(
    const float* __restrict__ q, const float* __restrict__ k,
    const float* __restrict__ v, const float* __restrict__ b,
    float* __restrict__ attn)
{
    __shared__ float vt[128][17];
    __shared__ float ew[104];

    const int lane = threadIdx.x;
    const int bid  = blockIdx.x;
    const int h    = bid & 7;
    const int i0   = (bid >> 3) * 8;
    const int base = i0 - SPAN;          // first row of the staged region

    // ---- stage V rows [base, base+128) into LDS ----
    #pragma unroll
    for (int rep = 0; rep < 2; ++rep) {
        const int r = rep * 64 + lane;
        int j = base + r;
        j = j < 0 ? 0 : (j > N - 1 ? N - 1 : j);
        const float4* vp = (const float4*)(v + (size_t)j * E + h * D);
        #pragma unroll
        for (int qt = 0; qt < 4; ++qt) {
            const float4 t = vp[qt];
            vt[r][qt * 4 + 0] = t.x; vt[r][qt * 4 + 1] = t.y;
            vt[r][qt * 4 + 2] = t.z; vt[r][qt * 4 + 3] = t.w;
        }
    }

    // ---- K/B(feature) rows for this lane's two positions -> registers ----
    const int p0 = base + lane;
    const int p1 = p0 + 64;
    const bool in0 = (p0 >= 0) && (p0 < N);
    const bool in1 = (p1 >= 0) && (p1 < N);
    const int c0 = p0 < 0 ? 0 : (p0 > N - 1 ? N - 1 : p0);
    const int c1 = p1 < 0 ? 0 : (p1 > N - 1 ? N - 1 : p1);

    float k0[16], k1[16], g0[16], g1[16];
    {
        const float4* kp0 = (const float4*)(k + (size_t)c0 * E + h * D);
        const float4* kp1 = (const float4*)(k + (size_t)c1 * E + h * D);
        const float4* gp0 = (const float4*)(b + (size_t)c0 * E + h * D);
        const float4* gp1 = (const float4*)(b + (size_t)c1 * E + h * D);
        #pragma unroll
        for (int x = 0; x < 4; ++x) {
            float4 t;
            t = kp0[x]; k0[4*x]=t.x; k0[4*x+1]=t.y; k0[4*x+2]=t.z; k0[4*x+3]=t.w;
            t = kp1[x]; k1[4*x]=t.x; k1[4*x+1]=t.y; k1[4*x+2]=t.z; k1[4*x+3]=t.w;
            t = gp0[x]; g0[4*x]=t.x; g0[4*x+1]=t.y; g0[4*x+2]=t.z; g0[4*x+3]=t.w;
            t = gp1[x]; g1[4*x]=t.x; g1[4*x+1]=t.y; g1[4*x+2]=t.z; g1[4*x+3]=t.w;
        }
    }
    __syncthreads();

    const float scale = 1.0f / 64.0f;    // 1/sqrt(4096)
    const int d = lane & 15;
    const int g = lane >> 4;

    for (int r = 0; r < 8; ++r) {
        // Q and B(query) for row i0+r: wave-uniform addresses -> scalar loads
        const float* qp = q + (size_t)(i0 + r) * E + h * D;
        const float* bp = b + (size_t)(i0 + r) * E + h * D;

        float sq0 = 0.f, sb0 = 0.f, sq1 = 0.f, sb1 = 0.f;
        #pragma unroll
        for (int x = 0; x < 16; ++x) {
            const float qv = qp[x];
            const float bv = bp[x];
            sq0 = fmaf(qv, k0[x], sq0);
            sq1 = fmaf(qv, k1[x], sq1);
            sb0 = fmaf(bv, g0[x], sb0);
            sb1 = fmaf(bv, g1[x], sb1);
        }
        // window membership: pos0 valid iff lane >= r, pos1 valid iff lane <= r+36
        const bool valid0 = in0 && (lane >= r);
        const bool valid1 = in1 && (lane <= r + 36);
        const float s0 = valid0 ? sq0 * scale + sb0 : -INFINITY;
        const float s1 = valid1 ? sq1 * scale + sb1 : -INFINITY;

        float m = fmaxf(s0, s1);
        #pragma unroll
        for (int off = 32; off; off >>= 1) m = fmaxf(m, __shfl_xor(m, off));

        const float e0 = __expf(s0 - m);   // -inf -> 0
        const float e1 = __expf(s1 - m);

        float sum = e0 + e1;
        #pragma unroll
        for (int off = 32; off; off >>= 1) sum += __shfl_xor(sum, off);
        const float inv = 1.0f / sum;

        // transpose probs to window coordinates: w0 = lane-r, w1 = 64+lane-r
        if (lane >= r)      ew[lane - r]      = e0;
        if (lane <= r + 36) ew[64 + lane - r] = e1;
        __syncthreads();

        // PV: lane = (d, g); group g covers w = g, g+4, ..., plus w=100 for g=0
        float acc = 0.f;
        #pragma unroll
        for (int it = 0; it < 25; ++it) {
            const int w = g + 4 * it;
            acc = fmaf(ew[w], vt[w + r][d], acc);
        }
        if (g == 0) acc = fmaf(ew[100], vt[100 + r][d], acc);

        acc += __shfl_xor(acc, 16);
        acc += __shfl_xor(acc, 32);

        if (lane < D) attn[(size_t)(i0 + r) * E + h * D + lane] = acc * inv;
        __syncthreads();
    }
}

// ---------------------------------------------------------------------------
// Kernel 3: output projection  out = attn @ Wo + bo  (same GEMM template)
// ---------------------------------------------------------------------------
__global__ __launch_bounds__(128) void out_kernel(
    const float* __restrict__ attn, const float* __restrict__ Wo,
    const float* __restrict__ bo, float* __restrict__ out)
{
    __shared__ float xs[8][E];
    __shared__ float part[2 * 8 * 132];

    const int tid  = threadIdx.x;
    const int c4   = tid & 31;
    const int r0   = ((tid >> 5) & 1) * 4;
    const int h    = tid >> 6;
    const int row0 = blockIdx.x * 8;

    #pragma unroll
    for (int rr = 0; rr < 2; ++rr) {
        const int idx = tid + 128 * rr;
        const int row = idx >> 5, q = idx & 31;
        *(float4*)&xs[row][q * 4] =
            ((const float4*)(attn + (size_t)(row0 + row) * E))[q];
    }
    __syncthreads();

    float4 acc[4];
    #pragma unroll
    for (int i = 0; i < 4; ++i) acc[i] = make_float4(0.f, 0.f, 0.f, 0.f);
    gemm_half_8x128(&xs[0][0], Wo, h, c4, r0, acc);
    combine_store(part, acc, h, c4, r0, tid, bo, out, row0);
}

// ---------------------------------------------------------------------------
extern "C" void kernel_launch(void* const* d_in, const int* in_sizes, int n_in,
                              void* d_out, int out_size, void* d_ws, size_t ws_size,
                              hipStream_t stream) {
    const float* query     = (const float*)d_in[0];
    const float* key       = (const float*)d_in[1];
    const float* value     = (const float*)d_in[2];
    const float* attn_bias = (const float*)d_in[3];
    const float* Wq  = (const float*)d_in[4];
    const float* bq  = (const float*)d_in[5];
    const float* Wk  = (const float*)d_in[6];
    const float* bk  = (const float*)d_in[7];
    const float* Wv  = (const float*)d_in[8];
    const float* bv  = (const float*)d_in[9];
    const float* Wo  = (const float*)d_in[10];
    const float* bo  = (const float*)d_in[11];
    const float* Wfe = (const float*)d_in[12];
    const float* bfe = (const float*)d_in[13];

    float* ws = (float*)d_ws;
    const int NE = N * E;
    float* qw    = ws;
    float* kw    = ws + 1 * NE;
    float* vw    = ws + 2 * NE;
    float* bw    = ws + 3 * NE;
    float* attnw = ws + 4 * NE;

    proj_kernel<<<N / 8, 128, 0, stream>>>(query, key, value, attn_bias,
                                           Wq, bq, Wk, bk, Wv, bv, Wfe, bfe,
                                           qw, kw, vw, bw);
    attn_kernel<<<(N / 8) * H, 64, 0, stream>>>(qw, kw, vw, bw, attnw);
    out_kernel<<<N / 8, 128, 0, stream>>>(attnw, Wo, bo, (float*)d_out);
}